// Round 3
// baseline (685.752 us; speedup 1.0000x reference)
//
#include <hip/hip_runtime.h>

#define T_TOK 2048
#define HD    2048
#define NE    32
#define ID    768
#define TOPK  8
#define NPAIR (T_TOK * TOPK)

typedef short bf16x8 __attribute__((ext_vector_type(8)));
typedef float f32x4  __attribute__((ext_vector_type(4)));

__device__ inline unsigned short f2bf(float f) {
    unsigned u = __builtin_bit_cast(unsigned, f);
    u += 0x7FFF + ((u >> 16) & 1);          // round-to-nearest-even
    return (unsigned short)(u >> 16);
}

__device__ inline void gload16(const void* g, void* l) {
    __builtin_amdgcn_global_load_lds(
        (const __attribute__((address_space(1))) unsigned*)g,
        (__attribute__((address_space(3))) unsigned*)l, 16, 0, 0);
}

// XCD-chunked swizzle: consecutive work-ids land on one XCD (L2 reuse of weight slices)
__device__ inline int xcd_swz(int x, int nblk) {
    int chunk = nblk >> 3;                   // nblk % 8 == 0 for all our grids
    return (x & 7) * chunk + (x >> 3);
}

// ---------------- X -> bf16 ----------------
__global__ void cvt_x(const float* __restrict__ x, unsigned short* __restrict__ x16) {
    int i = blockIdx.x * blockDim.x + threadIdx.x;       // one thread = 8 elems
    const float4* src = (const float4*)x + (size_t)i * 2;
    float4 a = src[0], b = src[1];
    uint4 r;
    r.x = (unsigned)f2bf(a.x) | ((unsigned)f2bf(a.y) << 16);
    r.y = (unsigned)f2bf(a.z) | ((unsigned)f2bf(a.w) << 16);
    r.z = (unsigned)f2bf(b.x) | ((unsigned)f2bf(b.y) << 16);
    r.w = (unsigned)f2bf(b.z) | ((unsigned)f2bf(b.w) << 16);
    *(uint4*)(x16 + (size_t)i * 8) = r;
}

// ---------------- weight transpose + cvt: [R][C] fp32 -> [C][R] bf16 (vectorized) ----------------
__global__ void transpose_cvt(const float* __restrict__ in, unsigned short* __restrict__ out,
                              int R, int C) {
    int e = blockIdx.z;
    int r0 = blockIdx.y * 64, c0 = blockIdx.x * 64;
    const float* src = in + (size_t)e * R * C;
    unsigned short* dst = out + (size_t)e * R * C;
    __shared__ float tile[64][65];           // odd stride: 2-way banks both phases (free)
    int tid = threadIdx.x;
    #pragma unroll
    for (int j = 0; j < 4; ++j) {            // 16B loads: 4/thread
        int idx = tid + 256 * j;             // 0..1023
        int rr = idx >> 4, c4 = (idx & 15) * 4;
        float4 v = *(const float4*)&src[(size_t)(r0 + rr) * C + c0 + c4];
        tile[rr][c4] = v.x; tile[rr][c4 + 1] = v.y; tile[rr][c4 + 2] = v.z; tile[rr][c4 + 3] = v.w;
    }
    __syncthreads();
    #pragma unroll
    for (int j = 0; j < 2; ++j) {            // 16B stores (8 bf16): 2/thread
        int idx = tid + 256 * j;             // 0..511
        int cc = idx >> 3, r8 = (idx & 7) * 8;
        uint4 o;
        unsigned* po = (unsigned*)&o;
        #pragma unroll
        for (int q = 0; q < 4; ++q)
            po[q] = (unsigned)f2bf(tile[r8 + 2 * q][cc]) |
                    ((unsigned)f2bf(tile[r8 + 2 * q + 1][cc]) << 16);
        *(uint4*)&dst[(size_t)(c0 + cc) * R + r0 + r8] = o;
    }
}

// ---------------- router ----------------
__global__ void router_kernel(const float* __restrict__ x, const float* __restrict__ wg,
                              int* __restrict__ topk_idx, float* __restrict__ topk_w,
                              int* __restrict__ counts) {
    int t = blockIdx.x;
    int tid = threadIdx.x;
    int e = tid & 31, seg = tid >> 5;                    // 32 experts x 8 H-segments
    const float* xr = x + (size_t)t * HD + seg * 256;
    const float* wp = wg + (size_t)(seg * 256) * NE + e;
    float acc = 0.f;
    #pragma unroll 4
    for (int j = 0; j < 256; ++j) acc += xr[j] * wp[j * NE];
    __shared__ float part[8][33];
    __shared__ float lg[32];
    part[seg][e] = acc;
    __syncthreads();
    if (tid < 32) {
        float s = 0.f;
        #pragma unroll
        for (int g = 0; g < 8; ++g) s += part[g][tid];
        lg[tid] = s;
    }
    __syncthreads();
    if (tid == 0) {
        float m = lg[0];
        for (int i = 1; i < 32; ++i) m = fmaxf(m, lg[i]);
        for (int i = 0; i < 32; ++i) lg[i] = __expf(lg[i] - m);
        int   idxs[TOPK]; float wv[TOPK]; float wsum = 0.f;
        #pragma unroll
        for (int k = 0; k < TOPK; ++k) {
            float best = -1.f; int bi = 0;
            for (int i = 0; i < 32; ++i) if (lg[i] > best) { best = lg[i]; bi = i; }
            idxs[k] = bi; wv[k] = best; wsum += best; lg[bi] = -1.f;
        }
        #pragma unroll
        for (int k = 0; k < TOPK; ++k) {
            topk_idx[t * TOPK + k] = idxs[k];
            topk_w[t * TOPK + k]   = wv[k] / wsum;
            atomicAdd(&counts[idxs[k]], 1);
        }
    }
}

__global__ void offsets_kernel(const int* __restrict__ counts, int* __restrict__ offsets,
                               int* __restrict__ cursor) {
    if (threadIdx.x == 0 && blockIdx.x == 0) {
        int run = 0;
        for (int e = 0; e < NE; ++e) { offsets[e] = run; cursor[e] = run; run += counts[e]; }
    }
}

__global__ void scatter_kernel(const int* __restrict__ topk_idx, int* __restrict__ cursor,
                               int* __restrict__ token_list) {
    int i = blockIdx.x * 256 + threadIdx.x;
    int e = topk_idx[i];
    int pos = atomicAdd(&cursor[e], 1);
    token_list[pos] = i;
}

// ---------------- GEMM1: act = silu(X Wg) * (X Wu); tile 128t x 128i ----------------
__global__ __launch_bounds__(256, 2)
void gemm1_kernel(const unsigned short* __restrict__ X16,
                  const unsigned short* __restrict__ WG, const unsigned short* __restrict__ WU,
                  const int* __restrict__ token_list, const int* __restrict__ counts,
                  const int* __restrict__ offsets, unsigned short* __restrict__ act16) {
    int f = xcd_swz(blockIdx.x, 32 * 6 * 16);
    int e = f / 96, rem = f % 96;
    int it = rem / 16, tt = rem % 16;        // tt innermost: same (e,it) group on one XCD
    int ne = counts[e];
    int row0 = tt * 128;
    if (row0 >= ne) return;
    int base = offsets[e];
    int i0 = it * 128;

    __shared__ __align__(16) unsigned short As[128 * 64];   // linear [row][64k], 128B rows
    __shared__ __align__(16) unsigned short Bg[128 * 64];
    __shared__ __align__(16) unsigned short Bu[128 * 64];
    __shared__ int rowTok[128];

    int tid = threadIdx.x;
    if (tid < 128) {
        int r = row0 + tid;
        rowTok[tid] = (r < ne) ? (token_list[base + r] >> 3) : 0;
    }
    __syncthreads();

    int lane = tid & 63, w = tid >> 6;
    int sub = lane & 7, lrow = lane >> 3;

    const unsigned short* aP[4]; const unsigned short* gP[4]; const unsigned short* uP[4];
    #pragma unroll
    for (int c = 0; c < 4; ++c) {
        int q = w * 4 + c;
        int r = q * 8 + lrow;
        int chunk = (sub ^ (r & 7)) * 8;                  // source-side swizzle (rule #21)
        aP[c] = X16 + (size_t)rowTok[r] * HD + chunk;
        gP[c] = WG + ((size_t)e * ID + i0 + r) * HD + chunk;
        uP[c] = WU + ((size_t)e * ID + i0 + r) * HD + chunk;
    }

    f32x4 accg[4][4], accu[4][4];
    #pragma unroll
    for (int m = 0; m < 4; ++m)
        #pragma unroll
        for (int n = 0; n < 4; ++n) {
            f32x4 z = {0.f, 0.f, 0.f, 0.f};
            accg[m][n] = z; accu[m][n] = z;
        }

    int wm = w >> 1, wn = w & 1, l15 = lane & 15, lhi = lane >> 4;
    const bf16x8* Af = (const bf16x8*)As;
    const bf16x8* Gf = (const bf16x8*)Bg;
    const bf16x8* Uf = (const bf16x8*)Bu;

    for (int k0 = 0; k0 < HD; k0 += 64) {
        #pragma unroll
        for (int c = 0; c < 4; ++c) {
            int q = w * 4 + c;
            gload16(aP[c] + k0, (char*)As + q * 1024);
            gload16(gP[c] + k0, (char*)Bg + q * 1024);
            gload16(uP[c] + k0, (char*)Bu + q * 1024);
        }
        __syncthreads();
        #pragma unroll
        for (int ks = 0; ks < 2; ++ks) {
            int cc = ks * 4 + lhi;
            bf16x8 a[4], bg[4], bu[4];
            #pragma unroll
            for (int m = 0; m < 4; ++m) { int r = wm * 64 + m * 16 + l15; a[m] = Af[r * 8 + (cc ^ (r & 7))]; }
            #pragma unroll
            for (int n = 0; n < 4; ++n) {
                int r = wn * 64 + n * 16 + l15;
                bg[n] = Gf[r * 8 + (cc ^ (r & 7))];
                bu[n] = Uf[r * 8 + (cc ^ (r & 7))];
            }
            #pragma unroll
            for (int m = 0; m < 4; ++m)
                #pragma unroll
                for (int n = 0; n < 4; ++n) {
                    accg[m][n] = __builtin_amdgcn_mfma_f32_16x16x32_bf16(a[m], bg[n], accg[m][n], 0, 0, 0);
                    accu[m][n] = __builtin_amdgcn_mfma_f32_16x16x32_bf16(a[m], bu[n], accu[m][n], 0, 0, 0);
                }
        }
        __syncthreads();
    }

    #pragma unroll
    for (int m = 0; m < 4; ++m) {
        int rb = wm * 64 + m * 16 + lhi * 4;
        #pragma unroll
        for (int q = 0; q < 4; ++q) {
            int r = rb + q;
            if (row0 + r < ne) {
                size_t orow = (size_t)(base + row0 + r) * ID + i0 + wn * 64;
                #pragma unroll
                for (int n = 0; n < 4; ++n) {
                    float g = accg[m][n][q], uu = accu[m][n][q];
                    float a = g / (1.f + __expf(-g)) * uu;
                    act16[orow + n * 16 + l15] = f2bf(a);
                }
            }
        }
    }
}

// ---------------- GEMM2: out[t,:] += w * (act Wd); tile 128t x 256h ----------------
__global__ __launch_bounds__(256, 2)
void gemm2_kernel(const unsigned short* __restrict__ act16, const unsigned short* __restrict__ WD,
                  const int* __restrict__ token_list, const int* __restrict__ counts,
                  const int* __restrict__ offsets, const float* __restrict__ topk_w,
                  float* __restrict__ out) {
    int f = xcd_swz(blockIdx.x, 32 * 8 * 16);
    int e = f / 128, rem = f % 128;
    int ht = rem / 16, tt = rem % 16;
    int ne = counts[e];
    int row0 = tt * 128;
    if (row0 >= ne) return;
    int base = offsets[e];
    int h0 = ht * 256;

    __shared__ __align__(16) unsigned short As[128 * 64];   // A: 128 pair-rows x 64k
    __shared__ __align__(16) unsigned short Bs[256 * 64];   // B: 256 h-rows x 64k
    __shared__ int   rowTok[128];
    __shared__ float rowW[128];

    int tid = threadIdx.x;
    if (tid < 128) {
        int r = row0 + tid;
        if (r < ne) { int v = token_list[base + r]; rowTok[tid] = v >> 3; rowW[tid] = topk_w[v]; }
        else        { rowTok[tid] = 0;              rowW[tid] = 0.f; }
    }
    __syncthreads();

    int lane = tid & 63, w = tid >> 6;
    int sub = lane & 7, lrow = lane >> 3;

    const unsigned short* aP[4]; const unsigned short* bP[8];
    #pragma unroll
    for (int c = 0; c < 4; ++c) {            // A: 16 instrs, 4/wave
        int q = w * 4 + c;
        int r = q * 8 + lrow;
        int chunk = (sub ^ (r & 7)) * 8;
        int pr = base + row0 + r;
        if (pr > NPAIR - 1) pr = NPAIR - 1;
        aP[c] = act16 + (size_t)pr * ID + chunk;
    }
    #pragma unroll
    for (int c = 0; c < 8; ++c) {            // B: 32 instrs, 8/wave
        int q = w * 8 + c;
        int r = q * 8 + lrow;
        int chunk = (sub ^ (r & 7)) * 8;
        bP[c] = WD + ((size_t)e * HD + h0 + r) * ID + chunk;
    }

    f32x4 acc[4][8];
    #pragma unroll
    for (int m = 0; m < 4; ++m)
        #pragma unroll
        for (int n = 0; n < 8; ++n) { f32x4 z = {0.f, 0.f, 0.f, 0.f}; acc[m][n] = z; }

    int wm = w >> 1, wn = w & 1, l15 = lane & 15, lhi = lane >> 4;
    const bf16x8* Af = (const bf16x8*)As;
    const bf16x8* Bf = (const bf16x8*)Bs;

    for (int k0 = 0; k0 < ID; k0 += 64) {
        #pragma unroll
        for (int c = 0; c < 4; ++c) {
            int q = w * 4 + c;
            gload16(aP[c] + k0, (char*)As + q * 1024);
        }
        #pragma unroll
        for (int c = 0; c < 8; ++c) {
            int q = w * 8 + c;
            gload16(bP[c] + k0, (char*)Bs + q * 1024);
        }
        __syncthreads();
        #pragma unroll
        for (int ks = 0; ks < 2; ++ks) {
            int cc = ks * 4 + lhi;
            bf16x8 a[4], b[8];
            #pragma unroll
            for (int m = 0; m < 4; ++m) { int r = wm * 64 + m * 16 + l15; a[m] = Af[r * 8 + (cc ^ (r & 7))]; }
            #pragma unroll
            for (int n = 0; n < 8; ++n) { int r = wn * 128 + n * 16 + l15; b[n] = Bf[r * 8 + (cc ^ (r & 7))]; }
            #pragma unroll
            for (int m = 0; m < 4; ++m)
                #pragma unroll
                for (int n = 0; n < 8; ++n)
                    acc[m][n] = __builtin_amdgcn_mfma_f32_16x16x32_bf16(a[m], b[n], acc[m][n], 0, 0, 0);
        }
        __syncthreads();
    }

    #pragma unroll
    for (int m = 0; m < 4; ++m) {
        int rb = wm * 64 + m * 16 + lhi * 4;
        #pragma unroll
        for (int q = 0; q < 4; ++q) {
            int r = rb + q;
            if (row0 + r < ne) {
                int tok = rowTok[r];
                float wgt = rowW[r];
                float* orow = out + (size_t)tok * HD + h0 + wn * 128;
                #pragma unroll
                for (int n = 0; n < 8; ++n)
                    atomicAdd(&orow[n * 16 + l15], acc[m][n][q] * wgt);
            }
        }
    }
}

extern "C" void kernel_launch(void* const* d_in, const int* in_sizes, int n_in,
                              void* d_out, int out_size, void* d_ws, size_t ws_size,
                              hipStream_t stream) {
    const float* x   = (const float*)d_in[0];
    const float* wg  = (const float*)d_in[1];
    const float* wgp = (const float*)d_in[2];
    const float* wup = (const float*)d_in[3];
    const float* wdp = (const float*)d_in[4];
    float* out = (float*)d_out;

    char* ws = (char*)d_ws;
    size_t off = 0;
    unsigned short* X16   = (unsigned short*)(ws + off); off += (size_t)T_TOK * HD * 2;   // 8 MB
    unsigned short* act16 = (unsigned short*)(ws + off); off += (size_t)NPAIR * ID * 2;   // 24 MB
    int*   topk_idx   = (int*)(ws + off);   off += NPAIR * 4;
    float* topk_w     = (float*)(ws + off); off += NPAIR * 4;
    int*   token_list = (int*)(ws + off);   off += NPAIR * 4;
    int*   counts     = (int*)(ws + off);   off += 256;
    int*   offsets    = (int*)(ws + off);   off += 256;
    int*   cursor     = (int*)(ws + off);   off += 256;
    unsigned short* WG = (unsigned short*)(ws + off); off += (size_t)NE * ID * HD * 2;    // 100.7 MB
    unsigned short* WU = (unsigned short*)(ws + off); off += (size_t)NE * ID * HD * 2;
    unsigned short* WD = (unsigned short*)(ws + off); off += (size_t)NE * HD * ID * 2;
    (void)in_sizes; (void)n_in; (void)out_size; (void)ws_size;

    hipMemsetAsync(counts, 0, 256, stream);
    hipMemsetAsync(d_out, 0, (size_t)T_TOK * HD * 4, stream);

    cvt_x<<<T_TOK * HD / (256 * 8), 256, 0, stream>>>(x, X16);
    router_kernel<<<T_TOK, 256, 0, stream>>>(x, wg, topk_idx, topk_w, counts);
    offsets_kernel<<<1, 64, 0, stream>>>(counts, offsets, cursor);
    scatter_kernel<<<NPAIR / 256, 256, 0, stream>>>(topk_idx, cursor, token_list);

    // pre-transpose + cvt weights: gate/up [H][I]->[I][H], down [I][H]->[H][I]
    transpose_cvt<<<dim3(ID / 64, HD / 64, NE), 256, 0, stream>>>(wgp, WG, HD, ID);
    transpose_cvt<<<dim3(ID / 64, HD / 64, NE), 256, 0, stream>>>(wup, WU, HD, ID);
    transpose_cvt<<<dim3(HD / 64, ID / 64, NE), 256, 0, stream>>>(wdp, WD, ID, HD);

    gemm1_kernel<<<32 * 6 * 16, 256, 0, stream>>>(X16, WG, WU, token_list, counts, offsets, act16);
    gemm2_kernel<<<32 * 8 * 16, 256, 0, stream>>>(act16, WD, token_list, counts, offsets, topk_w, out);
}

// Round 4
// 656.374 us; speedup vs baseline: 1.0448x; 1.0448x over previous
//
#include <hip/hip_runtime.h>

#define T_TOK 2048
#define HD    2048
#define NE    32
#define ID    768
#define TOPK  8
#define NPAIR (T_TOK * TOPK)
#define MAXT  160                            // max padded tiles: NPAIR/128 + NE

typedef short bf16x8 __attribute__((ext_vector_type(8)));
typedef float f32x4  __attribute__((ext_vector_type(4)));

__device__ inline unsigned short f2bf(float f) {
    unsigned u = __builtin_bit_cast(unsigned, f);
    u += 0x7FFF + ((u >> 16) & 1);          // round-to-nearest-even
    return (unsigned short)(u >> 16);
}

__device__ inline void gload16(const void* g, void* l) {
    __builtin_amdgcn_global_load_lds(
        (const __attribute__((address_space(1))) unsigned*)g,
        (__attribute__((address_space(3))) unsigned*)l, 16, 0, 0);
}

// ---------------- X -> bf16 ----------------
__global__ void cvt_x(const float* __restrict__ x, unsigned short* __restrict__ x16) {
    int i = blockIdx.x * blockDim.x + threadIdx.x;       // one thread = 8 elems
    const float4* src = (const float4*)x + (size_t)i * 2;
    float4 a = src[0], b = src[1];
    uint4 r;
    r.x = (unsigned)f2bf(a.x) | ((unsigned)f2bf(a.y) << 16);
    r.y = (unsigned)f2bf(a.z) | ((unsigned)f2bf(a.w) << 16);
    r.z = (unsigned)f2bf(b.x) | ((unsigned)f2bf(b.y) << 16);
    r.w = (unsigned)f2bf(b.z) | ((unsigned)f2bf(b.w) << 16);
    *(uint4*)(x16 + (size_t)i * 8) = r;
}

// ---------------- weight transpose + cvt: [R][C] fp32 -> [C][R] bf16 (vectorized) ----------------
__global__ void transpose_cvt(const float* __restrict__ in, unsigned short* __restrict__ out,
                              int R, int C) {
    int e = blockIdx.z;
    int r0 = blockIdx.y * 64, c0 = blockIdx.x * 64;
    const float* src = in + (size_t)e * R * C;
    unsigned short* dst = out + (size_t)e * R * C;
    __shared__ float tile[64][65];           // odd stride: 2-way banks both phases (free)
    int tid = threadIdx.x;
    #pragma unroll
    for (int j = 0; j < 4; ++j) {            // 16B loads: 4/thread
        int idx = tid + 256 * j;             // 0..1023
        int rr = idx >> 4, c4 = (idx & 15) * 4;
        float4 v = *(const float4*)&src[(size_t)(r0 + rr) * C + c0 + c4];
        tile[rr][c4] = v.x; tile[rr][c4 + 1] = v.y; tile[rr][c4 + 2] = v.z; tile[rr][c4 + 3] = v.w;
    }
    __syncthreads();
    #pragma unroll
    for (int j = 0; j < 2; ++j) {            // 16B stores (8 bf16): 2/thread
        int idx = tid + 256 * j;             // 0..511
        int cc = idx >> 3, r8 = (idx & 7) * 8;
        uint4 o;
        unsigned* po = (unsigned*)&o;
        #pragma unroll
        for (int q = 0; q < 4; ++q)
            po[q] = (unsigned)f2bf(tile[r8 + 2 * q][cc]) |
                    ((unsigned)f2bf(tile[r8 + 2 * q + 1][cc]) << 16);
        *(uint4*)&dst[(size_t)(c0 + cc) * R + r0 + r8] = o;
    }
}

// ---------------- router ----------------
__global__ void router_kernel(const float* __restrict__ x, const float* __restrict__ wg,
                              int* __restrict__ topk_idx, float* __restrict__ topk_w,
                              int* __restrict__ counts) {
    int t = blockIdx.x;
    int tid = threadIdx.x;
    int e = tid & 31, seg = tid >> 5;                    // 32 experts x 8 H-segments
    const float* xr = x + (size_t)t * HD + seg * 256;
    const float* wp = wg + (size_t)(seg * 256) * NE + e;
    float acc = 0.f;
    #pragma unroll 4
    for (int j = 0; j < 256; ++j) acc += xr[j] * wp[j * NE];
    __shared__ float part[8][33];
    __shared__ float lg[32];
    part[seg][e] = acc;
    __syncthreads();
    if (tid < 32) {
        float s = 0.f;
        #pragma unroll
        for (int g = 0; g < 8; ++g) s += part[g][tid];
        lg[tid] = s;
    }
    __syncthreads();
    if (tid == 0) {
        float m = lg[0];
        for (int i = 1; i < 32; ++i) m = fmaxf(m, lg[i]);
        for (int i = 0; i < 32; ++i) lg[i] = __expf(lg[i] - m);
        int   idxs[TOPK]; float wv[TOPK]; float wsum = 0.f;
        #pragma unroll
        for (int k = 0; k < TOPK; ++k) {
            float best = -1.f; int bi = 0;
            for (int i = 0; i < 32; ++i) if (lg[i] > best) { best = lg[i]; bi = i; }
            idxs[k] = bi; wv[k] = best; wsum += best; lg[bi] = -1.f;
        }
        #pragma unroll
        for (int k = 0; k < TOPK; ++k) {
            topk_idx[t * TOPK + k] = idxs[k];
            topk_w[t * TOPK + k]   = wv[k] / wsum;
            atomicAdd(&counts[idxs[k]], 1);
        }
    }
}

// ---------------- build padded tile table (1 thread; 32 iters, negligible) ----------------
__global__ void build_tiles(const int* __restrict__ counts, int* __restrict__ cursor,
                            int* __restrict__ tE, int* __restrict__ tStart,
                            int* __restrict__ tCnt) {
    if (threadIdx.x == 0 && blockIdx.x == 0) {
        int run = 0, nt = 0;
        for (int e = 0; e < NE; ++e) {
            cursor[e] = run;                              // scatter base for this expert
            int c = counts[e];
            int nte = (c + 127) >> 7;
            for (int j = 0; j < nte; ++j) {
                tE[nt] = e;
                tStart[nt] = run + j * 128;               // global padded row
                tCnt[nt] = (c - j * 128 < 128) ? (c - j * 128) : 128;
                ++nt;
            }
            run += nte * 128;
        }
        for (; nt < MAXT; ++nt) { tE[nt] = -1; tStart[nt] = 0; tCnt[nt] = 0; }
    }
}

__global__ void scatter_kernel(const int* __restrict__ topk_idx, int* __restrict__ cursor,
                               int* __restrict__ token_list) {
    int i = blockIdx.x * 256 + threadIdx.x;
    int e = topk_idx[i];
    int pos = atomicAdd(&cursor[e], 1);
    token_list[pos] = i;
}

// ---------------- GEMM1: act = silu(X Wg) * (X Wu); tile 128pair x 128i ----------------
__global__ __launch_bounds__(256, 2)
void gemm1_kernel(const unsigned short* __restrict__ X16,
                  const unsigned short* __restrict__ WG, const unsigned short* __restrict__ WU,
                  const int* __restrict__ token_list,
                  const int* __restrict__ tE, const int* __restrict__ tStart,
                  const int* __restrict__ tCnt, unsigned short* __restrict__ act16) {
    int tile = blockIdx.x / 6, it = blockIdx.x % 6;      // consecutive blocks share A-tile
    int e = tE[tile];
    if (e < 0) return;
    int start = tStart[tile], cnt = tCnt[tile];
    int i0 = it * 128;

    __shared__ __align__(16) unsigned short As[128 * 64];   // linear [row][64k], 128B rows
    __shared__ __align__(16) unsigned short Bg[128 * 64];
    __shared__ __align__(16) unsigned short Bu[128 * 64];
    __shared__ int rowTok[128];

    int tid = threadIdx.x;
    if (tid < 128)
        rowTok[tid] = (tid < cnt) ? (token_list[start + tid] >> 3) : 0;
    __syncthreads();

    int lane = tid & 63, w = tid >> 6;
    int sub = lane & 7, lrow = lane >> 3;

    const unsigned short* aP[4]; const unsigned short* gP[4]; const unsigned short* uP[4];
    #pragma unroll
    for (int c = 0; c < 4; ++c) {
        int q = w * 4 + c;
        int r = q * 8 + lrow;
        int chunk = (sub ^ (r & 7)) * 8;                  // source-side swizzle (rule #21)
        aP[c] = X16 + (size_t)rowTok[r] * HD + chunk;
        gP[c] = WG + ((size_t)e * ID + i0 + r) * HD + chunk;
        uP[c] = WU + ((size_t)e * ID + i0 + r) * HD + chunk;
    }

    f32x4 accg[4][4], accu[4][4];
    #pragma unroll
    for (int m = 0; m < 4; ++m)
        #pragma unroll
        for (int n = 0; n < 4; ++n) {
            f32x4 z = {0.f, 0.f, 0.f, 0.f};
            accg[m][n] = z; accu[m][n] = z;
        }

    int wm = w >> 1, wn = w & 1, l15 = lane & 15, lhi = lane >> 4;
    const bf16x8* Af = (const bf16x8*)As;
    const bf16x8* Gf = (const bf16x8*)Bg;
    const bf16x8* Uf = (const bf16x8*)Bu;

    for (int k0 = 0; k0 < HD; k0 += 64) {
        #pragma unroll
        for (int c = 0; c < 4; ++c) {
            int q = w * 4 + c;
            gload16(aP[c] + k0, (char*)As + q * 1024);
            gload16(gP[c] + k0, (char*)Bg + q * 1024);
            gload16(uP[c] + k0, (char*)Bu + q * 1024);
        }
        __syncthreads();
        #pragma unroll
        for (int ks = 0; ks < 2; ++ks) {
            int cc = ks * 4 + lhi;
            bf16x8 a[4], bg[4], bu[4];
            #pragma unroll
            for (int m = 0; m < 4; ++m) { int r = wm * 64 + m * 16 + l15; a[m] = Af[r * 8 + (cc ^ (r & 7))]; }
            #pragma unroll
            for (int n = 0; n < 4; ++n) {
                int r = wn * 64 + n * 16 + l15;
                bg[n] = Gf[r * 8 + (cc ^ (r & 7))];
                bu[n] = Uf[r * 8 + (cc ^ (r & 7))];
            }
            #pragma unroll
            for (int m = 0; m < 4; ++m)
                #pragma unroll
                for (int n = 0; n < 4; ++n) {
                    accg[m][n] = __builtin_amdgcn_mfma_f32_16x16x32_bf16(a[m], bg[n], accg[m][n], 0, 0, 0);
                    accu[m][n] = __builtin_amdgcn_mfma_f32_16x16x32_bf16(a[m], bu[n], accu[m][n], 0, 0, 0);
                }
        }
        __syncthreads();
    }

    // epilogue: silu(g)*u -> bf16; write ALL rows (pad rows masked by weight 0 in gemm2)
    #pragma unroll
    for (int m = 0; m < 4; ++m) {
        int rb = wm * 64 + m * 16 + lhi * 4;
        #pragma unroll
        for (int q = 0; q < 4; ++q) {
            int r = rb + q;
            size_t orow = (size_t)(start + r) * ID + i0 + wn * 64;
            #pragma unroll
            for (int n = 0; n < 4; ++n) {
                float g = accg[m][n][q], uu = accu[m][n][q];
                float a = g / (1.f + __expf(-g)) * uu;
                act16[orow + n * 16 + l15] = f2bf(a);
            }
        }
    }
}

// ---------------- GEMM2: out[t,:] += w * (act Wd); tile 128pair x 256h ----------------
__global__ __launch_bounds__(256, 2)
void gemm2_kernel(const unsigned short* __restrict__ act16, const unsigned short* __restrict__ WD,
                  const int* __restrict__ token_list,
                  const int* __restrict__ tE, const int* __restrict__ tStart,
                  const int* __restrict__ tCnt, const float* __restrict__ topk_w,
                  float* __restrict__ out) {
    int tile = blockIdx.x / 8, ht = blockIdx.x % 8;
    int e = tE[tile];
    if (e < 0) return;
    int start = tStart[tile], cnt = tCnt[tile];
    int h0 = ht * 256;

    __shared__ __align__(16) unsigned short As[128 * 64];   // A: 128 pair-rows x 64k
    __shared__ __align__(16) unsigned short Bs[256 * 64];   // B: 256 h-rows x 64k
    __shared__ int   rowTok[128];
    __shared__ float rowW[128];

    int tid = threadIdx.x;
    if (tid < 128) {
        if (tid < cnt) { int v = token_list[start + tid]; rowTok[tid] = v >> 3; rowW[tid] = topk_w[v]; }
        else           { rowTok[tid] = 0;                 rowW[tid] = 0.f; }
    }
    __syncthreads();

    int lane = tid & 63, w = tid >> 6;
    int sub = lane & 7, lrow = lane >> 3;

    const unsigned short* aP[4]; const unsigned short* bP[8];
    #pragma unroll
    for (int c = 0; c < 4; ++c) {            // A: 16 instrs, 4/wave
        int q = w * 4 + c;
        int r = q * 8 + lrow;
        int chunk = (sub ^ (r & 7)) * 8;
        aP[c] = act16 + (size_t)(start + r) * ID + chunk;   // padded rows always valid
    }
    #pragma unroll
    for (int c = 0; c < 8; ++c) {            // B: 32 instrs, 8/wave
        int q = w * 8 + c;
        int r = q * 8 + lrow;
        int chunk = (sub ^ (r & 7)) * 8;
        bP[c] = WD + ((size_t)e * HD + h0 + r) * ID + chunk;
    }

    f32x4 acc[4][8];
    #pragma unroll
    for (int m = 0; m < 4; ++m)
        #pragma unroll
        for (int n = 0; n < 8; ++n) { f32x4 z = {0.f, 0.f, 0.f, 0.f}; acc[m][n] = z; }

    int wm = w >> 1, wn = w & 1, l15 = lane & 15, lhi = lane >> 4;
    const bf16x8* Af = (const bf16x8*)As;
    const bf16x8* Bf = (const bf16x8*)Bs;

    for (int k0 = 0; k0 < ID; k0 += 64) {
        #pragma unroll
        for (int c = 0; c < 4; ++c) {
            int q = w * 4 + c;
            gload16(aP[c] + k0, (char*)As + q * 1024);
        }
        #pragma unroll
        for (int c = 0; c < 8; ++c) {
            int q = w * 8 + c;
            gload16(bP[c] + k0, (char*)Bs + q * 1024);
        }
        __syncthreads();
        #pragma unroll
        for (int ks = 0; ks < 2; ++ks) {
            int cc = ks * 4 + lhi;
            bf16x8 a[4], b[8];
            #pragma unroll
            for (int m = 0; m < 4; ++m) { int r = wm * 64 + m * 16 + l15; a[m] = Af[r * 8 + (cc ^ (r & 7))]; }
            #pragma unroll
            for (int n = 0; n < 8; ++n) { int r = wn * 128 + n * 16 + l15; b[n] = Bf[r * 8 + (cc ^ (r & 7))]; }
            #pragma unroll
            for (int m = 0; m < 4; ++m)
                #pragma unroll
                for (int n = 0; n < 8; ++n)
                    acc[m][n] = __builtin_amdgcn_mfma_f32_16x16x32_bf16(a[m], b[n], acc[m][n], 0, 0, 0);
        }
        __syncthreads();
    }

    #pragma unroll
    for (int m = 0; m < 4; ++m) {
        int rb = wm * 64 + m * 16 + lhi * 4;
        #pragma unroll
        for (int q = 0; q < 4; ++q) {
            int r = rb + q;
            if (r < cnt) {
                int tok = rowTok[r];
                float wgt = rowW[r];
                float* orow = out + (size_t)tok * HD + h0 + wn * 128;
                #pragma unroll
                for (int n = 0; n < 8; ++n)
                    atomicAdd(&orow[n * 16 + l15], acc[m][n][q] * wgt);
            }
        }
    }
}

extern "C" void kernel_launch(void* const* d_in, const int* in_sizes, int n_in,
                              void* d_out, int out_size, void* d_ws, size_t ws_size,
                              hipStream_t stream) {
    const float* x   = (const float*)d_in[0];
    const float* wg  = (const float*)d_in[1];
    const float* wgp = (const float*)d_in[2];
    const float* wup = (const float*)d_in[3];
    const float* wdp = (const float*)d_in[4];
    float* out = (float*)d_out;

    char* ws = (char*)d_ws;
    size_t off = 0;
    unsigned short* X16   = (unsigned short*)(ws + off); off += (size_t)T_TOK * HD * 2;      // 8 MB
    unsigned short* act16 = (unsigned short*)(ws + off); off += (size_t)MAXT * 128 * ID * 2; // 31.5 MB
    int*   topk_idx   = (int*)(ws + off);   off += NPAIR * 4;
    float* topk_w     = (float*)(ws + off); off += NPAIR * 4;
    int*   token_list = (int*)(ws + off);   off += MAXT * 128 * 4;
    int*   counts     = (int*)(ws + off);   off += 256;
    int*   cursor     = (int*)(ws + off);   off += 256;
    int*   tE         = (int*)(ws + off);   off += MAXT * 4;
    int*   tStart     = (int*)(ws + off);   off += MAXT * 4;
    int*   tCnt       = (int*)(ws + off);   off += MAXT * 4;
    off = (off + 255) & ~(size_t)255;
    unsigned short* WG = (unsigned short*)(ws + off); off += (size_t)NE * ID * HD * 2;       // 100.7 MB
    unsigned short* WU = (unsigned short*)(ws + off); off += (size_t)NE * ID * HD * 2;
    unsigned short* WD = (unsigned short*)(ws + off); off += (size_t)NE * HD * ID * 2;
    (void)in_sizes; (void)n_in; (void)out_size; (void)ws_size;

    hipMemsetAsync(counts, 0, 256, stream);
    hipMemsetAsync(d_out, 0, (size_t)T_TOK * HD * 4, stream);

    cvt_x<<<T_TOK * HD / (256 * 8), 256, 0, stream>>>(x, X16);
    router_kernel<<<T_TOK, 256, 0, stream>>>(x, wg, topk_idx, topk_w, counts);
    build_tiles<<<1, 64, 0, stream>>>(counts, cursor, tE, tStart, tCnt);
    scatter_kernel<<<NPAIR / 256, 256, 0, stream>>>(topk_idx, cursor, token_list);

    // pre-transpose + cvt weights: gate/up [H][I]->[I][H], down [I][H]->[H][I]
    transpose_cvt<<<dim3(ID / 64, HD / 64, NE), 256, 0, stream>>>(wgp, WG, HD, ID);
    transpose_cvt<<<dim3(ID / 64, HD / 64, NE), 256, 0, stream>>>(wup, WU, HD, ID);
    transpose_cvt<<<dim3(HD / 64, ID / 64, NE), 256, 0, stream>>>(wdp, WD, ID, HD);

    gemm1_kernel<<<MAXT * 6, 256, 0, stream>>>(X16, WG, WU, token_list, tE, tStart, tCnt, act16);
    gemm2_kernel<<<MAXT * 8, 256, 0, stream>>>(act16, WD, token_list, tE, tStart, tCnt, topk_w, out);
}

// Round 5
// 634.502 us; speedup vs baseline: 1.0808x; 1.0345x over previous
//
#include <hip/hip_runtime.h>

#define T_TOK 2048
#define HD    2048
#define NE    32
#define ID    768
#define TOPK  8
#define NPAIR (T_TOK * TOPK)
#define MAXT  160                            // max padded tiles: NPAIR/128 + NE

typedef short bf16x8 __attribute__((ext_vector_type(8)));
typedef float f32x4  __attribute__((ext_vector_type(4)));

__device__ inline unsigned short f2bf(float f) {
    unsigned u = __builtin_bit_cast(unsigned, f);
    u += 0x7FFF + ((u >> 16) & 1);          // round-to-nearest-even
    return (unsigned short)(u >> 16);
}

__device__ inline void gload16(const void* g, void* l) {
    __builtin_amdgcn_global_load_lds(
        (const __attribute__((address_space(1))) unsigned*)g,
        (__attribute__((address_space(3))) unsigned*)l, 16, 0, 0);
}

// ================= fused prep: 3x transpose_cvt + cvt_x + router in one dispatch =================
// Transpose tile 64x64: [R][C] f32 -> [C][R] bf16.
// LDS: bf16 tile stored column-major rows of 64 elems, stride 72 elems (144B, 16B-aligned),
// XOR-swizzled in 16B units: sw = t ^ ((c>>1)&7).

#define NT_GU 12288                          // (HD/64)*(ID/64)*NE = 32*12*32
#define NT_D  12288                          // (ID/64)*(HD/64)*NE
#define NB_CVT 2048                          // T_TOK*HD/(256*8)
#define NB_RTR 2048                          // T_TOK

__device__ inline void transpose_tile(const float* __restrict__ src, unsigned short* __restrict__ dst,
                                      int R, int C, int r0, int c0, char* lds) {
    int tid = threadIdx.x;
    // phase 1: 4 rows x float4 per thread -> 4x ds_write_b64 (column fragments)
    int rq = tid >> 4;                       // 0..15 (row quad)
    int c4 = (tid & 15) * 4;                 // 0..60
    const float* s0 = src + (size_t)(r0 + 4 * rq) * C + c0 + c4;
    float4 L0 = *(const float4*)(s0);
    float4 L1 = *(const float4*)(s0 + C);
    float4 L2 = *(const float4*)(s0 + 2 * C);
    float4 L3 = *(const float4*)(s0 + 3 * C);
    int t = rq >> 1, lo = rq & 1;
    const float* a0 = &L0.x; const float* a1 = &L1.x;
    const float* a2 = &L2.x; const float* a3 = &L3.x;
    #pragma unroll
    for (int q = 0; q < 4; ++q) {
        int c = c4 + q;
        int sw = t ^ ((c >> 1) & 7);
        unsigned w0 = (unsigned)f2bf(a0[q]) | ((unsigned)f2bf(a1[q]) << 16);
        unsigned w1 = (unsigned)f2bf(a2[q]) | ((unsigned)f2bf(a3[q]) << 16);
        uint2 wv = {w0, w1};
        *(uint2*)(lds + c * 144 + sw * 16 + lo * 8) = wv;
    }
    __syncthreads();
    // phase 2: ds_read_b128 + contiguous 16B stores (8 lanes = 128B run per dst row)
    #pragma unroll
    for (int jj = 0; jj < 2; ++jj) {
        int idx = tid + 256 * jj;            // 0..511
        int c = idx >> 3, tt = idx & 7;
        int sw = tt ^ ((c >> 1) & 7);
        uint4 v = *(const uint4*)(lds + c * 144 + sw * 16);
        *(uint4*)&dst[(size_t)(c0 + c) * R + r0 + 8 * tt] = v;
    }
}

__global__ __launch_bounds__(256)
void prep_kernel(const float* __restrict__ x, const float* __restrict__ wg,
                 const float* __restrict__ wgp, const float* __restrict__ wup,
                 const float* __restrict__ wdp,
                 unsigned short* __restrict__ X16,
                 unsigned short* __restrict__ WG, unsigned short* __restrict__ WU,
                 unsigned short* __restrict__ WD,
                 int* __restrict__ topk_idx, float* __restrict__ topk_w,
                 int* __restrict__ counts) {
    __shared__ __align__(16) char lds[64 * 144];
    int bid = blockIdx.x;
    if (bid < 2 * NT_GU) {                   // gate / up transposes: [HD][ID] -> [ID][HD]
        const float* src = (bid < NT_GU) ? wgp : wup;
        unsigned short* dst = (bid < NT_GU) ? WG : WU;
        int local = (bid < NT_GU) ? bid : bid - NT_GU;
        int e = local / 384, ti = local % 384;
        int r0 = (ti & 31) * 64, c0 = (ti >> 5) * 64;
        transpose_tile(src + (size_t)e * HD * ID, dst + (size_t)e * HD * ID,
                       ID, HD, 0, 0, lds);   // placeholder never taken (see below)
        // NOTE: call re-issued with correct R,C below -- see actual call
        return;
    }
    bid -= 2 * NT_GU;
    (void)bid;
}

// (prep_kernel above replaced by prep_all below -- kept out of launch path)

__global__ __launch_bounds__(256)
void prep_all(const float* __restrict__ x, const float* __restrict__ wg,
              const float* __restrict__ wgp, const float* __restrict__ wup,
              const float* __restrict__ wdp,
              unsigned short* __restrict__ X16,
              unsigned short* __restrict__ WG, unsigned short* __restrict__ WU,
              unsigned short* __restrict__ WD,
              int* __restrict__ topk_idx, float* __restrict__ topk_w,
              int* __restrict__ counts) {
    __shared__ __align__(16) char lds[64 * 144];
    int bid = blockIdx.x;

    if (bid < NT_GU) {                       // WG: [HD][ID] -> [ID][HD]
        int e = bid / 384, ti = bid % 384;
        int r0 = (ti & 31) * 64, c0 = (ti >> 5) * 64;   // r over HD(32 tiles), c over ID(12 tiles)
        transpose_tile(wgp + (size_t)e * HD * ID, WG + (size_t)e * HD * ID, HD, ID, r0, c0, lds);
        return;
    }
    bid -= NT_GU;
    if (bid < NT_GU) {                       // WU
        int e = bid / 384, ti = bid % 384;
        int r0 = (ti & 31) * 64, c0 = (ti >> 5) * 64;
        transpose_tile(wup + (size_t)e * HD * ID, WU + (size_t)e * HD * ID, HD, ID, r0, c0, lds);
        return;
    }
    bid -= NT_GU;
    if (bid < NT_D) {                        // WD: [ID][HD] -> [HD][ID]
        int e = bid / 384, ti = bid % 384;
        int r0 = (ti % 12) * 64, c0 = (ti / 12) * 64;   // r over ID(12 tiles), c over HD(32 tiles)
        transpose_tile(wdp + (size_t)e * ID * HD, WD + (size_t)e * ID * HD, ID, HD, r0, c0, lds);
        return;
    }
    bid -= NT_D;
    if (bid < NB_CVT) {                      // X -> bf16
        int i = bid * 256 + threadIdx.x;
        const float4* src = (const float4*)x + (size_t)i * 2;
        float4 a = src[0], b = src[1];
        uint4 r;
        r.x = (unsigned)f2bf(a.x) | ((unsigned)f2bf(a.y) << 16);
        r.y = (unsigned)f2bf(a.z) | ((unsigned)f2bf(a.w) << 16);
        r.z = (unsigned)f2bf(b.x) | ((unsigned)f2bf(b.y) << 16);
        r.w = (unsigned)f2bf(b.z) | ((unsigned)f2bf(b.w) << 16);
        *(uint4*)(X16 + (size_t)i * 8) = r;
        return;
    }
    bid -= NB_CVT;
    {                                        // router, one block per token
        int t = bid;
        int tid = threadIdx.x;
        int e = tid & 31, seg = tid >> 5;
        const float* xr = x + (size_t)t * HD + seg * 256;
        const float* wp = wg + (size_t)(seg * 256) * NE + e;
        float acc = 0.f;
        #pragma unroll 4
        for (int j = 0; j < 256; ++j) acc += xr[j] * wp[j * NE];
        float* part = (float*)lds;           // [8][33]
        float* lg = part + 8 * 33;           // [32]
        part[seg * 33 + e] = acc;
        __syncthreads();
        if (tid < 32) {
            float s = 0.f;
            #pragma unroll
            for (int g = 0; g < 8; ++g) s += part[g * 33 + tid];
            lg[tid] = s;
        }
        __syncthreads();
        if (tid == 0) {
            float m = lg[0];
            for (int i = 1; i < 32; ++i) m = fmaxf(m, lg[i]);
            for (int i = 0; i < 32; ++i) lg[i] = __expf(lg[i] - m);
            int   idxs[TOPK]; float wv[TOPK]; float wsum = 0.f;
            #pragma unroll
            for (int k = 0; k < TOPK; ++k) {
                float best = -1.f; int bi = 0;
                for (int i = 0; i < 32; ++i) if (lg[i] > best) { best = lg[i]; bi = i; }
                idxs[k] = bi; wv[k] = best; wsum += best; lg[bi] = -1.f;
            }
            #pragma unroll
            for (int k = 0; k < TOPK; ++k) {
                topk_idx[t * TOPK + k] = idxs[k];
                topk_w[t * TOPK + k]   = wv[k] / wsum;
                atomicAdd(&counts[idxs[k]], 1);
            }
        }
    }
}

// ---------------- build padded tile table (1 thread; negligible) ----------------
__global__ void build_tiles(const int* __restrict__ counts, int* __restrict__ cursor,
                            int* __restrict__ tE, int* __restrict__ tStart,
                            int* __restrict__ tCnt) {
    if (threadIdx.x == 0 && blockIdx.x == 0) {
        int run = 0, nt = 0;
        for (int e = 0; e < NE; ++e) {
            cursor[e] = run;
            int c = counts[e];
            int nte = (c + 127) >> 7;
            for (int j = 0; j < nte; ++j) {
                tE[nt] = e;
                tStart[nt] = run + j * 128;
                tCnt[nt] = (c - j * 128 < 128) ? (c - j * 128) : 128;
                ++nt;
            }
            run += nte * 128;
        }
        for (; nt < MAXT; ++nt) { tE[nt] = -1; tStart[nt] = 0; tCnt[nt] = 0; }
    }
}

__global__ void scatter_kernel(const int* __restrict__ topk_idx, int* __restrict__ cursor,
                               int* __restrict__ token_list) {
    int i = blockIdx.x * 256 + threadIdx.x;
    int e = topk_idx[i];
    int pos = atomicAdd(&cursor[e], 1);
    token_list[pos] = i;
}

// ---------------- GEMM1: act = silu(X Wg) * (X Wu); tile 128pair x 128i ----------------
__global__ __launch_bounds__(256, 2)
void gemm1_kernel(const unsigned short* __restrict__ X16,
                  const unsigned short* __restrict__ WG, const unsigned short* __restrict__ WU,
                  const int* __restrict__ token_list,
                  const int* __restrict__ tE, const int* __restrict__ tStart,
                  const int* __restrict__ tCnt, unsigned short* __restrict__ act16) {
    int tile = blockIdx.x / 6, it = blockIdx.x % 6;
    int e = tE[tile];
    if (e < 0) return;
    int start = tStart[tile], cnt = tCnt[tile];
    int i0 = it * 128;

    __shared__ __align__(16) unsigned short As[128 * 64];
    __shared__ __align__(16) unsigned short Bg[128 * 64];
    __shared__ __align__(16) unsigned short Bu[128 * 64];
    __shared__ int rowTok[128];

    int tid = threadIdx.x;
    if (tid < 128)
        rowTok[tid] = (tid < cnt) ? (token_list[start + tid] >> 3) : 0;
    __syncthreads();

    int lane = tid & 63, w = tid >> 6;
    int sub = lane & 7, lrow = lane >> 3;

    const unsigned short* aP[4]; const unsigned short* gP[4]; const unsigned short* uP[4];
    #pragma unroll
    for (int c = 0; c < 4; ++c) {
        int q = w * 4 + c;
        int r = q * 8 + lrow;
        int chunk = (sub ^ (r & 7)) * 8;
        aP[c] = X16 + (size_t)rowTok[r] * HD + chunk;
        gP[c] = WG + ((size_t)e * ID + i0 + r) * HD + chunk;
        uP[c] = WU + ((size_t)e * ID + i0 + r) * HD + chunk;
    }

    f32x4 accg[4][4], accu[4][4];
    #pragma unroll
    for (int m = 0; m < 4; ++m)
        #pragma unroll
        for (int n = 0; n < 4; ++n) {
            f32x4 z = {0.f, 0.f, 0.f, 0.f};
            accg[m][n] = z; accu[m][n] = z;
        }

    int wm = w >> 1, wn = w & 1, l15 = lane & 15, lhi = lane >> 4;
    const bf16x8* Af = (const bf16x8*)As;
    const bf16x8* Gf = (const bf16x8*)Bg;
    const bf16x8* Uf = (const bf16x8*)Bu;

    for (int k0 = 0; k0 < HD; k0 += 64) {
        #pragma unroll
        for (int c = 0; c < 4; ++c) {
            int q = w * 4 + c;
            gload16(aP[c] + k0, (char*)As + q * 1024);
            gload16(gP[c] + k0, (char*)Bg + q * 1024);
            gload16(uP[c] + k0, (char*)Bu + q * 1024);
        }
        __syncthreads();
        #pragma unroll
        for (int ks = 0; ks < 2; ++ks) {
            int cc = ks * 4 + lhi;
            bf16x8 a[4], bg[4], bu[4];
            #pragma unroll
            for (int m = 0; m < 4; ++m) { int r = wm * 64 + m * 16 + l15; a[m] = Af[r * 8 + (cc ^ (r & 7))]; }
            #pragma unroll
            for (int n = 0; n < 4; ++n) {
                int r = wn * 64 + n * 16 + l15;
                bg[n] = Gf[r * 8 + (cc ^ (r & 7))];
                bu[n] = Uf[r * 8 + (cc ^ (r & 7))];
            }
            #pragma unroll
            for (int m = 0; m < 4; ++m)
                #pragma unroll
                for (int n = 0; n < 4; ++n) {
                    accg[m][n] = __builtin_amdgcn_mfma_f32_16x16x32_bf16(a[m], bg[n], accg[m][n], 0, 0, 0);
                    accu[m][n] = __builtin_amdgcn_mfma_f32_16x16x32_bf16(a[m], bu[n], accu[m][n], 0, 0, 0);
                }
        }
        __syncthreads();
    }

    #pragma unroll
    for (int m = 0; m < 4; ++m) {
        int rb = wm * 64 + m * 16 + lhi * 4;
        #pragma unroll
        for (int q = 0; q < 4; ++q) {
            int r = rb + q;
            size_t orow = (size_t)(start + r) * ID + i0 + wn * 64;
            #pragma unroll
            for (int n = 0; n < 4; ++n) {
                float g = accg[m][n][q], uu = accu[m][n][q];
                float a = g / (1.f + __expf(-g)) * uu;
                act16[orow + n * 16 + l15] = f2bf(a);
            }
        }
    }
}

// ---------------- GEMM2: out[t,:] += w * (act Wd); tile 128pair x 256h ----------------
__global__ __launch_bounds__(256, 2)
void gemm2_kernel(const unsigned short* __restrict__ act16, const unsigned short* __restrict__ WD,
                  const int* __restrict__ token_list,
                  const int* __restrict__ tE, const int* __restrict__ tStart,
                  const int* __restrict__ tCnt, const float* __restrict__ topk_w,
                  float* __restrict__ out) {
    int tile = blockIdx.x / 8, ht = blockIdx.x % 8;
    int e = tE[tile];
    if (e < 0) return;
    int start = tStart[tile], cnt = tCnt[tile];
    int h0 = ht * 256;

    __shared__ __align__(16) unsigned short As[128 * 64];
    __shared__ __align__(16) unsigned short Bs[256 * 64];
    __shared__ int   rowTok[128];
    __shared__ float rowW[128];

    int tid = threadIdx.x;
    if (tid < 128) {
        if (tid < cnt) { int v = token_list[start + tid]; rowTok[tid] = v >> 3; rowW[tid] = topk_w[v]; }
        else           { rowTok[tid] = 0;                 rowW[tid] = 0.f; }
    }
    __syncthreads();

    int lane = tid & 63, w = tid >> 6;
    int sub = lane & 7, lrow = lane >> 3;

    const unsigned short* aP[4]; const unsigned short* bP[8];
    #pragma unroll
    for (int c = 0; c < 4; ++c) {
        int q = w * 4 + c;
        int r = q * 8 + lrow;
        int chunk = (sub ^ (r & 7)) * 8;
        aP[c] = act16 + (size_t)(start + r) * ID + chunk;
    }
    #pragma unroll
    for (int c = 0; c < 8; ++c) {
        int q = w * 8 + c;
        int r = q * 8 + lrow;
        int chunk = (sub ^ (r & 7)) * 8;
        bP[c] = WD + ((size_t)e * HD + h0 + r) * ID + chunk;
    }

    f32x4 acc[4][8];
    #pragma unroll
    for (int m = 0; m < 4; ++m)
        #pragma unroll
        for (int n = 0; n < 8; ++n) { f32x4 z = {0.f, 0.f, 0.f, 0.f}; acc[m][n] = z; }

    int wm = w >> 1, wn = w & 1, l15 = lane & 15, lhi = lane >> 4;
    const bf16x8* Af = (const bf16x8*)As;
    const bf16x8* Bf = (const bf16x8*)Bs;

    for (int k0 = 0; k0 < ID; k0 += 64) {
        #pragma unroll
        for (int c = 0; c < 4; ++c) {
            int q = w * 4 + c;
            gload16(aP[c] + k0, (char*)As + q * 1024);
        }
        #pragma unroll
        for (int c = 0; c < 8; ++c) {
            int q = w * 8 + c;
            gload16(bP[c] + k0, (char*)Bs + q * 1024);
        }
        __syncthreads();
        #pragma unroll
        for (int ks = 0; ks < 2; ++ks) {
            int cc = ks * 4 + lhi;
            bf16x8 a[4], b[8];
            #pragma unroll
            for (int m = 0; m < 4; ++m) { int r = wm * 64 + m * 16 + l15; a[m] = Af[r * 8 + (cc ^ (r & 7))]; }
            #pragma unroll
            for (int n = 0; n < 8; ++n) { int r = wn * 128 + n * 16 + l15; b[n] = Bf[r * 8 + (cc ^ (r & 7))]; }
            #pragma unroll
            for (int m = 0; m < 4; ++m)
                #pragma unroll
                for (int n = 0; n < 8; ++n)
                    acc[m][n] = __builtin_amdgcn_mfma_f32_16x16x32_bf16(a[m], b[n], acc[m][n], 0, 0, 0);
        }
        __syncthreads();
    }

    #pragma unroll
    for (int m = 0; m < 4; ++m) {
        int rb = wm * 64 + m * 16 + lhi * 4;
        #pragma unroll
        for (int q = 0; q < 4; ++q) {
            int r = rb + q;
            if (r < cnt) {
                int tok = rowTok[r];
                float wgt = rowW[r];
                float* orow = out + (size_t)tok * HD + h0 + wn * 128;
                #pragma unroll
                for (int n = 0; n < 8; ++n)
                    atomicAdd(&orow[n * 16 + l15], acc[m][n][q] * wgt);
            }
        }
    }
}

extern "C" void kernel_launch(void* const* d_in, const int* in_sizes, int n_in,
                              void* d_out, int out_size, void* d_ws, size_t ws_size,
                              hipStream_t stream) {
    const float* x   = (const float*)d_in[0];
    const float* wg  = (const float*)d_in[1];
    const float* wgp = (const float*)d_in[2];
    const float* wup = (const float*)d_in[3];
    const float* wdp = (const float*)d_in[4];
    float* out = (float*)d_out;

    char* ws = (char*)d_ws;
    size_t off = 0;
    unsigned short* X16   = (unsigned short*)(ws + off); off += (size_t)T_TOK * HD * 2;      // 8 MB
    unsigned short* act16 = (unsigned short*)(ws + off); off += (size_t)MAXT * 128 * ID * 2; // 31.5 MB
    int*   topk_idx   = (int*)(ws + off);   off += NPAIR * 4;
    float* topk_w     = (float*)(ws + off); off += NPAIR * 4;
    int*   token_list = (int*)(ws + off);   off += MAXT * 128 * 4;
    int*   counts     = (int*)(ws + off);   off += 256;
    int*   cursor     = (int*)(ws + off);   off += 256;
    int*   tE         = (int*)(ws + off);   off += MAXT * 4;
    int*   tStart     = (int*)(ws + off);   off += MAXT * 4;
    int*   tCnt       = (int*)(ws + off);   off += MAXT * 4;
    off = (off + 255) & ~(size_t)255;
    unsigned short* WG = (unsigned short*)(ws + off); off += (size_t)NE * ID * HD * 2;       // 100.7 MB
    unsigned short* WU = (unsigned short*)(ws + off); off += (size_t)NE * ID * HD * 2;
    unsigned short* WD = (unsigned short*)(ws + off); off += (size_t)NE * HD * ID * 2;
    (void)in_sizes; (void)n_in; (void)out_size; (void)ws_size;

    hipMemsetAsync(counts, 0, 256, stream);
    hipMemsetAsync(d_out, 0, (size_t)T_TOK * HD * 4, stream);

    // fused prep: WG/WU/WD transpose+cvt, X cvt, router -- one dispatch
    prep_all<<<NT_GU + NT_GU + NT_D + NB_CVT + NB_RTR, 256, 0, stream>>>(
        x, wg, wgp, wup, wdp, X16, WG, WU, WD, topk_idx, topk_w, counts);

    build_tiles<<<1, 64, 0, stream>>>(counts, cursor, tE, tStart, tCnt);
    scatter_kernel<<<NPAIR / 256, 256, 0, stream>>>(topk_idx, cursor, token_list);

    gemm1_kernel<<<MAXT * 6, 256, 0, stream>>>(X16, WG, WU, token_list, tE, tStart, tCnt, act16);
    gemm2_kernel<<<MAXT * 8, 256, 0, stream>>>(act16, WD, token_list, tE, tStart, tCnt, topk_w, out);
}